// Round 1
// baseline (205.834 us; speedup 1.0000x reference)
//
#include <hip/hip_runtime.h>

typedef unsigned short u16;
typedef unsigned int   u32;
typedef __bf16 bf16x8 __attribute__((ext_vector_type(8)));
typedef float  f32x4  __attribute__((ext_vector_type(4)));

#define LOG2E 1.4426950408889634f

// fp32 -> bf16 round-to-nearest-even
__device__ __forceinline__ u16 f2bf(float f) {
  union { float f; u32 u; } v; v.f = f;
  u32 r = v.u + 0x7fffu + ((v.u >> 16) & 1u);
  return (u16)(r >> 16);
}

#define GLOAD_LDS16(g, s) __builtin_amdgcn_global_load_lds( \
    (const __attribute__((address_space(1))) void*)(g),     \
    (__attribute__((address_space(3))) void*)(s), 16, 0, 0)

// ---------------- prep kernels ----------------

__global__ void k_convert(const float* __restrict__ in, u16* __restrict__ out) {
  int i = (blockIdx.x * 256 + threadIdx.x) * 8;
  float4 a = *(const float4*)(in + i);
  float4 b = *(const float4*)(in + i + 4);
  u16 o[8] = { f2bf(a.x), f2bf(a.y), f2bf(a.z), f2bf(a.w),
               f2bf(b.x), f2bf(b.y), f2bf(b.z), f2bf(b.w) };
  *(uint4*)(out + i) = *(const uint4*)o;
}

// W [1024][1024] f32 (k-major) -> WT [1024][1024] bf16 (n-major): WT[n][k] = W[k][n]
__global__ void k_transpose_w(const float* __restrict__ W, u16* __restrict__ WT) {
  __shared__ float tile[64][65];
  const int t = threadIdx.x;
  const int n0 = blockIdx.x * 64, k0 = blockIdx.y * 64;
  const int r = t >> 4, c4 = (t & 15) * 4;
  #pragma unroll
  for (int rr = 0; rr < 64; rr += 16) {
    float4 v = *(const float4*)(W + (size_t)(k0 + r + rr) * 1024 + n0 + c4);
    tile[r + rr][c4]     = v.x; tile[r + rr][c4 + 1] = v.y;
    tile[r + rr][c4 + 2] = v.z; tile[r + rr][c4 + 3] = v.w;
  }
  __syncthreads();
  #pragma unroll
  for (int rr = 0; rr < 64; rr += 16) {
    u16 o[4] = { f2bf(tile[c4][r + rr]),     f2bf(tile[c4 + 1][r + rr]),
                 f2bf(tile[c4 + 2][r + rr]), f2bf(tile[c4 + 3][r + rr]) };
    *(ushort4*)(WT + (size_t)(n0 + r + rr) * 1024 + k0 + c4) = *(const ushort4*)o;
  }
}

// ---------------- GEMM: C[M][N] = A[M][K] * BT[N][K]^T ----------------
// m97-verified structure: 128x128 tile, BK=32, 4 waves (2x2), global_load_lds w16.

template<int OUTF32>
__global__ __launch_bounds__(256) void k_gemm_bt(
    const u16* __restrict__ A, const u16* __restrict__ BT,
    void* __restrict__ Cv, const float* __restrict__ bias,
    int M, int N, int K) {
  __shared__ u16 lA[2][128 * 32];
  __shared__ u16 lB[2][128 * 32];
  const int t = threadIdx.x;
  const int l = t & 63, w = t >> 6;
  const int bM = blockIdx.y * 128, bN = blockIdx.x * 128;
  const int wr = w >> 1, wc = w & 1;
  const int NT = K >> 5;

  f32x4 acc[4][4] = {};

  const int fA  = w * 512 + l * 8;   // flat element index, linear LDS layout
  const int r0  = fA >> 5;           // row 0..63
  const int kc0 = fA & 31;           // k within tile

  auto stage = [&](int buf, int kt) {
    const u16* ga = A  + (size_t)(bM + r0) * K + kt * 32 + kc0;
    const u16* gb = BT + (size_t)(bN + r0) * K + kt * 32 + kc0;
    GLOAD_LDS16(ga, &lA[buf][w * 512]);
    GLOAD_LDS16(gb, &lB[buf][w * 512]);
    GLOAD_LDS16(ga + (size_t)64 * K, &lA[buf][2048 + w * 512]);
    GLOAD_LDS16(gb + (size_t)64 * K, &lB[buf][2048 + w * 512]);
  };

  stage(0, 0);
  __syncthreads();
  int buf = 0;
  for (int kt = 0; kt < NT; ++kt) {
    if (kt + 1 < NT) stage(buf ^ 1, kt + 1);
    bf16x8 af[4], bfr[4];
    #pragma unroll
    for (int m = 0; m < 4; ++m)
      af[m] = *(const bf16x8*)&lA[buf][(wr * 64 + m * 16 + (l & 15)) * 32 + (l >> 4) * 8];
    #pragma unroll
    for (int n = 0; n < 4; ++n)
      bfr[n] = *(const bf16x8*)&lB[buf][(wc * 64 + n * 16 + (l & 15)) * 32 + (l >> 4) * 8];
    #pragma unroll
    for (int m = 0; m < 4; ++m)
      #pragma unroll
      for (int n = 0; n < 4; ++n)
        acc[m][n] = __builtin_amdgcn_mfma_f32_16x16x32_bf16(af[m], bfr[n], acc[m][n], 0, 0, 0);
    __syncthreads();
    buf ^= 1;
  }

  #pragma unroll
  for (int m = 0; m < 4; ++m) {
    #pragma unroll
    for (int n = 0; n < 4; ++n) {
      const int row = bM + wr * 64 + m * 16 + (l >> 4) * 4;
      const int col = bN + wc * 64 + n * 16 + (l & 15);
      #pragma unroll
      for (int i = 0; i < 4; ++i) {
        if (OUTF32) ((float*)Cv)[(size_t)(row + i) * N + col] = acc[m][n][i] + bias[col];
        else        ((u16*)Cv)[(size_t)(row + i) * N + col]   = f2bf(acc[m][n][i]);
      }
    }
  }
}

// ---------------- flash attention (causal, no scale) ----------------
// grid (32 q-blocks, 32 bh). 4 waves x 16 q-rows. KV blocks of 64.
// QKV layout: [b*2048+t][3072]: cols 0..1023 Q, 1024..2047 K, 2048..3071 V.

__global__ __launch_bounds__(256) void k_attn(const u16* __restrict__ qkv,
                                              u16* __restrict__ ctx) {
  __shared__ u16 kl[64 * 72];        // K tile, padded stride 72
  __shared__ u16 vt[64 * 72];        // V^T tile [d][kpos], padded
  __shared__ u16 pl[4][16 * 72];     // per-wave P bounce

  const int t = threadIdx.x;
  const int l = t & 63, w = t >> 6;
  const int bh = blockIdx.y;
  const int b = bh >> 4, h = bh & 15;
  const int qb = blockIdx.x;
  const int q0 = qb * 64;

  const u16* base = qkv + (size_t)b * 2048 * 3072;

  bf16x8 qf[2];
  {
    const int qr = q0 + w * 16 + (l & 15);
    const u16* qp = base + (size_t)qr * 3072 + h * 64 + (l >> 4) * 8;
    qf[0] = *(const bf16x8*)qp;
    qf[1] = *(const bf16x8*)(qp + 32);
  }

  f32x4 oacc[4] = {};
  float m[4], lsum[4];
  #pragma unroll
  for (int i = 0; i < 4; ++i) { m[i] = -__builtin_inff(); lsum[i] = 0.f; }

  const int kr = t >> 2, kc = (t & 3) * 16;       // K staging: row, col
  const int vpi = t & 31, dg = (t >> 5) * 8;      // V staging: k-pair, d-group

  for (int kb = 0; kb <= qb; ++kb) {
    {
      const u16* kp = base + (size_t)(kb * 64 + kr) * 3072 + 1024 + h * 64 + kc;
      uint4 v0 = *(const uint4*)kp;
      uint4 v1 = *(const uint4*)(kp + 8);
      *(uint4*)&kl[kr * 72 + kc]     = v0;
      *(uint4*)&kl[kr * 72 + kc + 8] = v1;

      const u16* vp = base + (size_t)(kb * 64 + 2 * vpi) * 3072 + 2048 + h * 64 + dg;
      uint4 va4 = *(const uint4*)vp;
      uint4 vb4 = *(const uint4*)(vp + 3072);
      const u16* va = (const u16*)&va4;
      const u16* vb = (const u16*)&vb4;
      #pragma unroll
      for (int j = 0; j < 8; ++j) {
        u32 pk = (u32)va[j] | ((u32)vb[j] << 16);
        *(u32*)&vt[(dg + j) * 72 + 2 * vpi] = pk;
      }
    }
    __syncthreads();

    // S = Q K^T  (16 q-rows x 64 kpos)
    f32x4 s[4] = {};
    #pragma unroll
    for (int dc = 0; dc < 2; ++dc) {
      #pragma unroll
      for (int n = 0; n < 4; ++n) {
        bf16x8 kf = *(const bf16x8*)&kl[(n * 16 + (l & 15)) * 72 + dc * 32 + (l >> 4) * 8];
        s[n] = __builtin_amdgcn_mfma_f32_16x16x32_bf16(qf[dc], kf, s[n], 0, 0, 0);
      }
    }

    if (kb == qb) {  // diagonal block: causal mask
      #pragma unroll
      for (int n = 0; n < 4; ++n) {
        const int kpos = q0 + n * 16 + (l & 15);
        #pragma unroll
        for (int i = 0; i < 4; ++i) {
          const int qr = q0 + w * 16 + (l >> 4) * 4 + i;
          if (kpos > qr) s[n][i] = -__builtin_inff();
        }
      }
    }

    // online softmax (rows live on 16-lane groups; reduce over lane&15)
    float scl[4];
    #pragma unroll
    for (int i = 0; i < 4; ++i) {
      float mx = fmaxf(fmaxf(s[0][i], s[1][i]), fmaxf(s[2][i], s[3][i]));
      #pragma unroll
      for (int d = 1; d < 16; d <<= 1) mx = fmaxf(mx, __shfl_xor(mx, d, 64));
      const float mn = fmaxf(m[i], mx);
      scl[i] = exp2f((m[i] - mn) * LOG2E);
      m[i] = mn;
      float rs = 0.f;
      #pragma unroll
      for (int n = 0; n < 4; ++n) {
        const float e = exp2f((s[n][i] - mn) * LOG2E);
        s[n][i] = e;
        rs += e;
      }
      #pragma unroll
      for (int d = 1; d < 16; d <<= 1) rs += __shfl_xor(rs, d, 64);
      lsum[i] = lsum[i] * scl[i] + rs;
    }

    // P -> LDS (bf16, A-fragment layout bounce) + O rescale
    #pragma unroll
    for (int n = 0; n < 4; ++n) {
      #pragma unroll
      for (int i = 0; i < 4; ++i) {
        pl[w][((l >> 4) * 4 + i) * 72 + n * 16 + (l & 15)] = f2bf(s[n][i]);
        oacc[n][i] *= scl[i];
      }
    }
    asm volatile("s_waitcnt lgkmcnt(0)" ::: "memory");

    // O += P V
    #pragma unroll
    for (int kc2 = 0; kc2 < 2; ++kc2) {
      bf16x8 pf = *(const bf16x8*)&pl[w][(l & 15) * 72 + kc2 * 32 + (l >> 4) * 8];
      #pragma unroll
      for (int n = 0; n < 4; ++n) {
        bf16x8 vf = *(const bf16x8*)&vt[(n * 16 + (l & 15)) * 72 + kc2 * 32 + (l >> 4) * 8];
        oacc[n] = __builtin_amdgcn_mfma_f32_16x16x32_bf16(pf, vf, oacc[n], 0, 0, 0);
      }
    }
    __syncthreads();  // protect kl/vt before next stage
  }

  #pragma unroll
  for (int n = 0; n < 4; ++n) {
    #pragma unroll
    for (int i = 0; i < 4; ++i) {
      const int qr = q0 + w * 16 + (l >> 4) * 4 + i;
      ctx[(size_t)(b * 2048 + qr) * 1024 + h * 64 + n * 16 + (l & 15)] =
          f2bf(oacc[n][i] / lsum[i]);
    }
  }
}

// ---------------- launch ----------------

extern "C" void kernel_launch(void* const* d_in, const int* in_sizes, int n_in,
                              void* d_out, int out_size, void* d_ws, size_t ws_size,
                              hipStream_t stream) {
  const float* x  = (const float*)d_in[0];
  const float* Wq = (const float*)d_in[1];
  const float* Wk = (const float*)d_in[2];
  const float* Wv = (const float*)d_in[3];
  const float* Wo = (const float*)d_in[4];
  const float* bo = (const float*)d_in[5];
  float* out = (float*)d_out;
  char* ws = (char*)d_ws;

  // workspace layout (bytes): xb 0..8M, WqkvT 8..14M, WoT 14..16M,
  // QKV 16..40M, ctx 40..48M
  u16* xb    = (u16*)(ws);
  u16* WqkvT = (u16*)(ws + (8u  << 20));
  u16* WoT   = (u16*)(ws + (14u << 20));
  u16* QKV   = (u16*)(ws + (16u << 20));
  u16* ctx   = (u16*)(ws + (40u << 20));

  k_convert<<<2048, 256, 0, stream>>>(x, xb);
  k_transpose_w<<<dim3(16, 16), 256, 0, stream>>>(Wq, WqkvT);
  k_transpose_w<<<dim3(16, 16), 256, 0, stream>>>(Wk, WqkvT + (1u << 20));
  k_transpose_w<<<dim3(16, 16), 256, 0, stream>>>(Wv, WqkvT + (2u << 20));
  k_transpose_w<<<dim3(16, 16), 256, 0, stream>>>(Wo, WoT);

  // QKV = xb @ WqkvT^T : [4096][3072]
  k_gemm_bt<0><<<dim3(24, 32), 256, 0, stream>>>(xb, WqkvT, QKV, nullptr, 4096, 3072, 1024);
  // causal MHA -> ctx [4096][1024] bf16
  k_attn<<<dim3(32, 32), 256, 0, stream>>>(QKV, ctx);
  // out = ctx @ WoT^T + bo : fp32
  k_gemm_bt<1><<<dim3(8, 32), 256, 0, stream>>>(ctx, WoT, out, bo, 4096, 1024, 1024);
}

// Round 3
// 155.291 us; speedup vs baseline: 1.3255x; 1.3255x over previous
//
#include <hip/hip_runtime.h>

typedef unsigned short u16;
typedef unsigned int   u32;
typedef __bf16 bf16x8 __attribute__((ext_vector_type(8)));
typedef float  f32x4  __attribute__((ext_vector_type(4)));
typedef float  f32x16 __attribute__((ext_vector_type(16)));
typedef u32    u32x4  __attribute__((ext_vector_type(4)));

#define LOG2E 1.4426950408889634f

// fp32 -> bf16 round-to-nearest-even
__device__ __forceinline__ u16 f2bf(float f) {
  union { float f; u32 u; } v; v.f = f;
  u32 r = v.u + 0x7fffu + ((v.u >> 16) & 1u);
  return (u16)(r >> 16);
}

__device__ __forceinline__ u32 pack2(float lo, float hi) {
  return (u32)f2bf(lo) | ((u32)f2bf(hi) << 16);
}

#define GLOAD_LDS16(g, s) __builtin_amdgcn_global_load_lds( \
    (const __attribute__((address_space(1))) void*)(g),     \
    (__attribute__((address_space(3))) void*)(s), 16, 0, 0)

// ---------------- prep kernels ----------------

__global__ void k_convert(const float* __restrict__ in, u16* __restrict__ out) {
  int i = (blockIdx.x * 256 + threadIdx.x) * 8;
  float4 a = *(const float4*)(in + i);
  float4 b = *(const float4*)(in + i + 4);
  u16 o[8] = { f2bf(a.x), f2bf(a.y), f2bf(a.z), f2bf(a.w),
               f2bf(b.x), f2bf(b.y), f2bf(b.z), f2bf(b.w) };
  *(uint4*)(out + i) = *(const uint4*)o;
}

// W [1024][1024] f32 (k-major) -> WT [1024][1024] bf16 (n-major): WT[n][k] = W[k][n]
__global__ void k_transpose_w(const float* __restrict__ W, u16* __restrict__ WT) {
  __shared__ float tile[64][65];
  const int t = threadIdx.x;
  const int n0 = blockIdx.x * 64, k0 = blockIdx.y * 64;
  const int r = t >> 4, c4 = (t & 15) * 4;
  #pragma unroll
  for (int rr = 0; rr < 64; rr += 16) {
    float4 v = *(const float4*)(W + (size_t)(k0 + r + rr) * 1024 + n0 + c4);
    tile[r + rr][c4]     = v.x; tile[r + rr][c4 + 1] = v.y;
    tile[r + rr][c4 + 2] = v.z; tile[r + rr][c4 + 3] = v.w;
  }
  __syncthreads();
  #pragma unroll
  for (int rr = 0; rr < 64; rr += 16) {
    u16 o[4] = { f2bf(tile[c4][r + rr]),     f2bf(tile[c4 + 1][r + rr]),
                 f2bf(tile[c4 + 2][r + rr]), f2bf(tile[c4 + 3][r + rr]) };
    *(ushort4*)(WT + (size_t)(n0 + r + rr) * 1024 + k0 + c4) = *(const ushort4*)o;
  }
}

// V region of QKV (cols 2048..3071) -> VT[1024][4096] bf16: VT[d][tok] = V[tok][d]
__global__ void k_transpose_v(const u16* __restrict__ qkv, u16* __restrict__ vt) {
  __shared__ u16 tile[64][72];
  const int t = threadIdx.x;
  const int c0 = blockIdx.x * 64;   // d
  const int r0 = blockIdx.y * 64;   // token
  const int rr = t >> 3;            // 0..31
  const int cc = (t & 7) * 8;       // 0..56
  #pragma unroll
  for (int j = 0; j < 2; ++j) {
    int r = rr + j * 32;
    *(uint4*)&tile[r][cc] = *(const uint4*)(qkv + (size_t)(r0 + r) * 3072 + 2048 + c0 + cc);
  }
  __syncthreads();
  #pragma unroll
  for (int j = 0; j < 2; ++j) {
    int c = rr + j * 32;
    u16 o[8];
    #pragma unroll
    for (int k = 0; k < 8; ++k) o[k] = tile[cc + k][c];
    *(uint4*)(vt + (size_t)(c0 + c) * 4096 + r0 + cc) = *(const uint4*)o;
  }
}

// ---------------- GEMM: C[M][N] = A[M][K] * BT[N][K]^T ----------------

template<int OUTF32>
__global__ __launch_bounds__(256) void k_gemm_bt(
    const u16* __restrict__ A, const u16* __restrict__ BT,
    void* __restrict__ Cv, const float* __restrict__ bias,
    int M, int N, int K) {
  __shared__ u16 lA[2][128 * 32];
  __shared__ u16 lB[2][128 * 32];
  const int t = threadIdx.x;
  const int l = t & 63, w = t >> 6;
  const int bM = blockIdx.y * 128, bN = blockIdx.x * 128;
  const int wr = w >> 1, wc = w & 1;
  const int NT = K >> 5;

  f32x4 acc[4][4] = {};

  const int fA  = w * 512 + l * 8;
  const int r0  = fA >> 5;
  const int kc0 = fA & 31;

  auto stage = [&](int buf, int kt) {
    const u16* ga = A  + (size_t)(bM + r0) * K + kt * 32 + kc0;
    const u16* gb = BT + (size_t)(bN + r0) * K + kt * 32 + kc0;
    GLOAD_LDS16(ga, &lA[buf][w * 512]);
    GLOAD_LDS16(gb, &lB[buf][w * 512]);
    GLOAD_LDS16(ga + (size_t)64 * K, &lA[buf][2048 + w * 512]);
    GLOAD_LDS16(gb + (size_t)64 * K, &lB[buf][2048 + w * 512]);
  };

  stage(0, 0);
  __syncthreads();
  int buf = 0;
  for (int kt = 0; kt < NT; ++kt) {
    if (kt + 1 < NT) stage(buf ^ 1, kt + 1);
    bf16x8 af[4], bfr[4];
    #pragma unroll
    for (int m = 0; m < 4; ++m)
      af[m] = *(const bf16x8*)&lA[buf][(wr * 64 + m * 16 + (l & 15)) * 32 + (l >> 4) * 8];
    #pragma unroll
    for (int n = 0; n < 4; ++n)
      bfr[n] = *(const bf16x8*)&lB[buf][(wc * 64 + n * 16 + (l & 15)) * 32 + (l >> 4) * 8];
    #pragma unroll
    for (int m = 0; m < 4; ++m)
      #pragma unroll
      for (int n = 0; n < 4; ++n)
        acc[m][n] = __builtin_amdgcn_mfma_f32_16x16x32_bf16(af[m], bfr[n], acc[m][n], 0, 0, 0);
    __syncthreads();
    buf ^= 1;
  }

  #pragma unroll
  for (int m = 0; m < 4; ++m) {
    #pragma unroll
    for (int n = 0; n < 4; ++n) {
      const int row = bM + wr * 64 + m * 16 + (l >> 4) * 4;
      const int col = bN + wc * 64 + n * 16 + (l & 15);
      #pragma unroll
      for (int i = 0; i < 4; ++i) {
        if (OUTF32) ((float*)Cv)[(size_t)(row + i) * N + col] = acc[m][n][i] + bias[col];
        else        ((u16*)Cv)[(size_t)(row + i) * N + col]   = f2bf(acc[m][n][i]);
      }
    }
  }
}

// ---------------- flash attention (causal, no scale) ----------------
// Per-wave independent: 32 q-rows/wave via swapped mfma(K,Q) 32x32x16.
// No LDS, no barriers. S^T layout: lane col = qrow (l&31); reg r -> kpos
// (r&3)+8*(r>>2)+4*(l>>5)  [m74/m101-verified C/D layout].
// 512 blocks x 4 waves; waves paired (qt, 63-qt) -> every block 130 work units;
// blockIdx%8 pins 4 heads per XCD for K/VT L2 residency.

__global__ __launch_bounds__(256, 2) void k_attn(
    const u16* __restrict__ qkv, const u16* __restrict__ vtg, u16* __restrict__ ctx) {
  const int t = threadIdx.x;
  const int l = t & 63, w = t >> 6;
  const int hi = l >> 5, ln = l & 31;
  const int bidx = blockIdx.x;
  const int x = bidx & 7, g = bidx >> 3;
  const int bh = x * 4 + (g & 3);         // 0..31 ; 4 heads per XCD slot
  const int jj = g >> 2;                  // 0..15
  const int qp = jj * 4 + w;              // 0..63
  const int qt = (qp & 1) ? (63 - (qp >> 1)) : (qp >> 1);  // balanced pairing
  const int bb = bh >> 4, h = bh & 15;

  const size_t tokbase = (size_t)bb * 2048;

  // Q B-fragments: lane holds Q[q0+ln][ds*16 + hi*8 + j] (row-contiguous)
  bf16x8 qf[4];
  {
    const u16* qq = qkv + (tokbase + qt * 32 + ln) * 3072 + h * 64 + hi * 8;
    #pragma unroll
    for (int ds = 0; ds < 4; ++ds) qf[ds] = *(const bf16x8*)(qq + ds * 16);
  }

  // K A-fragment pointer (advances 32 rows/tile); V^T pointers (advance 32 cols/tile)
  const u16* kp  = qkv + (tokbase + ln) * 3072 + 1024 + h * 64 + hi * 8;
  const u16* vp0 = vtg + (size_t)(h * 64 + ln) * 4096 + tokbase + hi * 8;
  const u16* vp1 = vp0 + (size_t)32 * 4096;

  f32x16 oa = {}, ob = {};        // O cols 0..31 / 32..63 (lane col = d)
  float m = -__builtin_inff(), lh = 0.f;

  bf16x8 kA[4], kB[4];
  auto loadK = [&](bf16x8 (&kf)[4]) {
    #pragma unroll
    for (int ds = 0; ds < 4; ++ds) kf[ds] = *(const bf16x8*)(kp + ds * 16);
    kp += 32 * 3072;
  };

  auto process = [&](bf16x8 (&kf)[4], bool diag) {
    // V B-fragments for this tile (needed only after softmax -> latency hidden)
    bf16x8 v00 = *(const bf16x8*)(vp0);
    bf16x8 v01 = *(const bf16x8*)(vp0 + 16);
    bf16x8 v10 = *(const bf16x8*)(vp1);
    bf16x8 v11 = *(const bf16x8*)(vp1 + 16);
    vp0 += 32; vp1 += 32;   // FIX (R2 bug): one tile = 32 tokens, was advancing 64

    // S^T = K * Q^T  (accumulate over 4 d-steps)
    f32x16 sc = {};
    #pragma unroll
    for (int ds = 0; ds < 4; ++ds)
      sc = __builtin_amdgcn_mfma_f32_32x32x16_bf16(kf[ds], qf[ds], sc, 0, 0, 0);

    if (diag) {  // causal mask on the diagonal tile: kpos_loc > qrow_loc
      #pragma unroll
      for (int r = 0; r < 16; ++r) {
        const int kloc = (r & 3) + 8 * (r >> 2) + 4 * hi;
        if (kloc > ln) sc[r] = -__builtin_inff();
      }
    }

    // row max: in-lane over 16 + partner half via one shfl_xor(32)
    float pm = sc[0];
    #pragma unroll
    for (int r = 1; r < 16; ++r) pm = fmaxf(pm, sc[r]);
    pm = fmaxf(pm, __shfl_xor(pm, 32));

    // defer-max (T13): rescale O only when max grows > 8
    if (!__all(pm <= m + 8.0f)) {
      const float mn  = fmaxf(m, pm);
      const float scl = exp2f((m - mn) * LOG2E);
      m = mn;
      lh *= scl;
      #pragma unroll
      for (int r = 0; r < 16; ++r) {
        const float sr = __shfl(scl, (r & 3) + 8 * (r >> 2) + 4 * hi);
        oa[r] *= sr; ob[r] *= sr;
      }
    }

    float ph[16];
    #pragma unroll
    for (int r = 0; r < 16; ++r) ph[r] = exp2f((sc[r] - m) * LOG2E);
    float rs = 0.f;
    #pragma unroll
    for (int r = 0; r < 16; ++r) rs += ph[r];
    lh += rs;

    // pack P to bf16 pairs; redistribute halves for PV A-fragments
    u32 c0 = pack2(ph[0],  ph[1]),  c1 = pack2(ph[2],  ph[3]);
    u32 c2 = pack2(ph[4],  ph[5]),  c3 = pack2(ph[6],  ph[7]);
    u32 c4 = pack2(ph[8],  ph[9]),  c5 = pack2(ph[10], ph[11]);
    u32 c6 = pack2(ph[12], ph[13]), c7 = pack2(ph[14], ph[15]);
    const u32 s0 = __shfl_xor(c0, 32), s1 = __shfl_xor(c1, 32);
    const u32 s2 = __shfl_xor(c2, 32), s3 = __shfl_xor(c3, 32);
    const u32 s4 = __shfl_xor(c4, 32), s5 = __shfl_xor(c5, 32);
    const u32 s6 = __shfl_xor(c6, 32), s7 = __shfl_xor(c7, 32);
    const bool h0 = (hi == 0);
    u32x4 wa0 = { h0 ? c0 : s2, h0 ? c1 : s3, h0 ? s0 : c2, h0 ? s1 : c3 };
    u32x4 wa1 = { h0 ? c4 : s6, h0 ? c5 : s7, h0 ? s4 : c6, h0 ? s5 : c7 };
    bf16x8 pa0 = __builtin_bit_cast(bf16x8, wa0);
    bf16x8 pa1 = __builtin_bit_cast(bf16x8, wa1);

    // O += P V   (A = P[q][k], B = V[k][d] from VT rows)
    oa = __builtin_amdgcn_mfma_f32_32x32x16_bf16(pa0, v00, oa, 0, 0, 0);
    oa = __builtin_amdgcn_mfma_f32_32x32x16_bf16(pa1, v01, oa, 0, 0, 0);
    ob = __builtin_amdgcn_mfma_f32_32x32x16_bf16(pa0, v10, ob, 0, 0, 0);
    ob = __builtin_amdgcn_mfma_f32_32x32x16_bf16(pa1, v11, ob, 0, 0, 0);
  };

  loadK(kA);
  for (int kt = 0; kt <= qt; kt += 2) {
    const bool more1 = (kt + 1 <= qt);
    if (more1) loadK(kB);
    process(kA, kt == qt);
    if (more1) {
      if (kt + 2 <= qt) loadK(kA);
      process(kB, kt + 1 == qt);
    }
  }

  // epilogue: O / lsum, write ctx (64B-coalesced per half-wave)
  const float lf  = lh + __shfl_xor(lh, 32);
  const float rin = 1.0f / lf;
  u16* cb = ctx + (tokbase + qt * 32) * 1024 + h * 64 + ln;
  #pragma unroll
  for (int r = 0; r < 16; ++r) {
    const int rm = (r & 3) + 8 * (r >> 2) + 4 * hi;
    const float rr = __shfl(rin, rm);
    cb[(size_t)rm * 1024]      = f2bf(oa[r] * rr);
    cb[(size_t)rm * 1024 + 32] = f2bf(ob[r] * rr);
  }
}

// ---------------- launch ----------------

extern "C" void kernel_launch(void* const* d_in, const int* in_sizes, int n_in,
                              void* d_out, int out_size, void* d_ws, size_t ws_size,
                              hipStream_t stream) {
  const float* x  = (const float*)d_in[0];
  const float* Wq = (const float*)d_in[1];
  const float* Wk = (const float*)d_in[2];
  const float* Wv = (const float*)d_in[3];
  const float* Wo = (const float*)d_in[4];
  const float* bo = (const float*)d_in[5];
  float* out = (float*)d_out;
  char* ws = (char*)d_ws;

  // ws layout (bytes): [0,8M) xb, later reused as VT; [8M,14M) WqkvT;
  // [14M,16M) WoT; [16M,40M) QKV; [40M,48M) ctx
  u16* xb    = (u16*)(ws);
  u16* VT    = (u16*)(ws);                 // reuses xb after QKV GEMM
  u16* WqkvT = (u16*)(ws + (8u  << 20));
  u16* WoT   = (u16*)(ws + (14u << 20));
  u16* QKV   = (u16*)(ws + (16u << 20));
  u16* ctxb  = (u16*)(ws + (40u << 20));

  k_convert<<<2048, 256, 0, stream>>>(x, xb);
  k_transpose_w<<<dim3(16, 16), 256, 0, stream>>>(Wq, WqkvT);
  k_transpose_w<<<dim3(16, 16), 256, 0, stream>>>(Wk, WqkvT + (1u << 20));
  k_transpose_w<<<dim3(16, 16), 256, 0, stream>>>(Wv, WqkvT + (2u << 20));
  k_transpose_w<<<dim3(16, 16), 256, 0, stream>>>(Wo, WoT);

  // QKV = xb @ WqkvT^T : [4096][3072] bf16
  k_gemm_bt<0><<<dim3(24, 32), 256, 0, stream>>>(xb, WqkvT, QKV, nullptr, 4096, 3072, 1024);
  // V^T into global (xb region now dead)
  k_transpose_v<<<dim3(16, 64), 256, 0, stream>>>(QKV, VT);
  // causal MHA -> ctx [4096][1024] bf16
  k_attn<<<512, 256, 0, stream>>>(QKV, VT, ctxb);
  // out = ctx @ WoT^T + bo : fp32
  k_gemm_bt<1><<<dim3(8, 32), 256, 0, stream>>>(ctxb, WoT, out, bo, 4096, 1024, 1024);
}